// Round 11
// baseline (3254.627 us; speedup 1.0000x reference)
//
#include <hip/hip_runtime.h>
#include <math.h>

#define BB   64      // batch
#define TT_  1024    // sequence length
#define UU   512     // hidden units
#define VV   256     // vocab (output)
#define EE   256     // embedding dim
#define TC   256     // time chunk (4 dispatches)

__device__ __forceinline__ float tanh_fast(float x) {
    // tanh(x) = 1 - 2/(e^{2x}+1); abs err ~1e-6 (validated: absmax 6e-5 end-to-end)
    float e = __expf(x + x);
    return 1.f - 2.f * __builtin_amdgcn_rcpf(e + 1.f);
}

// hstage float4-index swizzle (R4/R6-measured: SQ_LDS_BANK_CONFLICT == 0)
__device__ __forceinline__ int swz(int a) {
    return a ^ (((a >> 3) & 7) ^ ((a >> 6) & 1));
}

// ---------------- E2 = emb @ Wx + b : [256, 512] ----------------
__global__ __launch_bounds__(512) void e2_kernel(
    const float* __restrict__ emb, const float* __restrict__ Wx,
    const float* __restrict__ bias, float* __restrict__ E2)
{
    const int v = blockIdx.x;
    const int u = threadIdx.x;
    float acc = bias[u];
    const float* er = emb + v * EE;
    #pragma unroll 8
    for (int e = 0; e < EE; ++e)
        acc = fmaf(er[e], Wx[e * UU + u], acc);
    E2[v * UU + u] = acc;
}

// ---------------- fused recurrence + logits -------------------------------
// 256 blocks (1/CU), 512 thr = 8 waves. bg = bid&31 (2 batches), ug = bid>>5.
// Group-of-8 blocks (same bg, same XCD under round-robin: bids == bg mod 8)
// exchange h via hpub[(slot,b,u)] = (tag<<32|fp32), dual-published (volatile
// sc0 + agent atomic). Poll = baseline-proven: 24 bounded sc0 rounds, then
// agent-scope spin with s_sleep (never hangs).
// R10 POST-MORTEM (5380cy/step): DS ~1500, VALU ~1880, scratch-weight vmem in
// parallel; ~2000cy = serial exchange chain (publish -> L2 visibility -> poll
// detect, each detect round a dependent ~250cy L2 RTT).
// R11: (a) EARLY-ISSUED POLL -- fire poll round-0 volatile loads right after
// our publish; check after logits -> round-0 RTT hides under ~200cy of logits
// FMA/shfl (peers publish symmetrically, so tags often visible by check time).
// (b) fused single ballot per round. (c) TC 128->256: 4 dispatches, halves
// launch + per-dispatch weight-reload overhead.
// Schedule per step: [pre-check/poll h(s-1)] -> stage -> lgkm-only barrier ->
// matvec (128 FMA, 8 h b128, h saved to regs) -> fold-reduce (9 shfl) -> tanh
// -> PUBLISH -> pre-issue poll loads for h(s) -> logits(s-1) from saved regs
// (hidden in exchange window). No atomics, no out memset.
__global__ __launch_bounds__(512)
void rnn_chunk_kernel(
    const int* __restrict__ toks, const float* __restrict__ E2,
    const float* __restrict__ Wh, const float* __restrict__ Wd,
    const float* __restrict__ bd,
    unsigned long long* hpub,     // [2][BB][UU] (tag,val) pairs
    float* out, int t0, int last)
{
    __shared__ __align__(16) float hstage[2][2][UU];   // 8 KB (swizzled)
    __shared__ __align__(16) float xps[2][2][64];      // 1 KB
    __shared__ int stok[2][TC];                        // 2 KB

    const int bid  = blockIdx.x;
    const int bg   = bid & 31;
    const int ug   = bid >> 5;
    const int tid  = threadIdx.x;
    const int w    = tid >> 6;
    const int lane = tid & 63;
    const int b0   = bg * 2;

    // roles: thread (quad, ks) does matvec units [ug*64+quad*4,+4) over
    // k [16ks,+16) AND logits v {ug*32+2quad, +1} over u [16ks,+16)
    const int qsel = lane >> 5;          // 0/1
    const int ks   = lane & 31;          // k/u slice [ks*16, +16)
    const int quad = w * 2 + qsel;       // [0,16)
    const int fmv  = ((ks >> 1) & 7) ^ ((ks >> 4) & 1);   // swz term, a = 4ks+g
    const int v0   = ug * 32 + quad * 2;

    // ---- Wh fragment (RA keeps in scratch -- measured best; vmem pipe
    //      overlaps the DS pipe) ----
    float4 whreg[16];                    // whreg[4g+m] = Wh[16ks+4g+m][ug*64+quad*4..+4]
    {
        const float4* Wh4 = (const float4*)Wh;   // [512][128]
        #pragma unroll
        for (int r = 0; r < 16; ++r)
            whreg[r] = Wh4[(ks * 16 + r) * 128 + ug * 16 + quad];
    }
    #pragma unroll
    for (int r = 0; r < 16; ++r) {
        float px = whreg[r].x, py = whreg[r].y, pz = whreg[r].z, pw = whreg[r].w;
        asm volatile("" : "+v"(px), "+v"(py), "+v"(pz), "+v"(pw));
        whreg[r] = make_float4(px, py, pz, pw);
    }

    // ---- Wd column pair -> registers/scratch (32 floats) ----
    float wdreg[32];                     // [j]=Wd[16ks+j][v0], [16+j]=..[v0+1]
    #pragma unroll
    for (int j = 0; j < 16; ++j) {
        const float2 wd2 = *(const float2*)(Wd + (ks * 16 + j) * VV + v0);
        wdreg[j]      = wd2.x;
        wdreg[16 + j] = wd2.y;
    }
    const float bdv0 = bd[v0];
    const float bdv1 = bd[v0 + 1];

    // ---- chunk tokens + xp(t0) staging ----
    {
        const int b = tid >> 8, q = tid & (TC - 1);
        stok[b][q] = toks[(b0 + b) * TT_ + t0 + q];
    }
    if (tid < 128) {
        const int b = tid >> 6, u = tid & 63;
        xps[0][b][u] = E2[toks[(b0 + b) * TT_ + t0] * UU + ug * 64 + u];
    }
    __syncthreads();

    // early-issued poll state (loads fired during prior iteration's logits)
    unsigned long long q0 = 0, q1 = 0;
    bool pre = false;

    for (int tt = 0; tt < TC; ++tt) {
        const int s  = t0 + tt;
        const int sl = (s - 1) & 1;

        // ---- poll h(s-1) (skip own slice except at chunk start) ----
        if (s > 0 && (w != ug || tt == 0)) {
            unsigned long long* a0 = hpub + ((size_t)sl * BB + b0) * UU + w * 64 + lane;
            unsigned long long* a1 = a0 + UU;
            volatile const unsigned long long* f0 = a0;
            volatile const unsigned long long* f1 = a1;
            const unsigned int want = (unsigned int)(s - 1);
            unsigned long long p0 = 0, p1 = 0;
            bool got = false;
            if (pre) {   // round 0 flew under the previous logits block
                p0 = q0; p1 = q1;
                got = (__ballot(((unsigned int)(p0 >> 32) == want) &&
                                ((unsigned int)(p1 >> 32) == want))
                       == 0xFFFFFFFFFFFFFFFFull);
            }
            if (!got) {
                for (int it = 0; it < 24; ++it) { // sc0 fast rounds (local-XCD L2)
                    p0 = *f0; p1 = *f1;
                    if (__ballot(((unsigned int)(p0 >> 32) == want) &&
                                 ((unsigned int)(p1 >> 32) == want))
                        == 0xFFFFFFFFFFFFFFFFull) { got = true; break; }
                }
            }
            if (!got) {                           // proven agent-scope fallback
                while (true) {
                    p0 = __hip_atomic_load(a0, __ATOMIC_RELAXED, __HIP_MEMORY_SCOPE_AGENT);
                    p1 = __hip_atomic_load(a1, __ATOMIC_RELAXED, __HIP_MEMORY_SCOPE_AGENT);
                    if (__ballot(((unsigned int)(p0 >> 32) == want) &&
                                 ((unsigned int)(p1 >> 32) == want))
                        == 0xFFFFFFFFFFFFFFFFull) break;
                    __builtin_amdgcn_s_sleep(1);
                }
            }
            // stage swizzled: u = w*64+lane -> float4 a = w*16+(lane>>2), elem lane&3
            const int aa = w * 16 + (lane >> 2);
            const int fi = swz(aa) * 4 + (lane & 3);
            hstage[sl][0][fi] = __uint_as_float((unsigned int)p0);
            hstage[sl][1][fi] = __uint_as_float((unsigned int)p1);
        }
        pre = false;
        // RAW barrier: order LDS (lgkmcnt) but let publish/out stores and
        // prefetch loads stay in flight (no vmcnt(0) drain).
        asm volatile("s_waitcnt lgkmcnt(0)" ::: "memory");
        __builtin_amdgcn_s_barrier();

        // ---- xp prefetch for s+1: issue load now, LDS-write after matvec ----
        float xpre = 0.f;
        const bool dopre = (tid < 128) && (tt + 1 < TC);
        if (dopre)
            xpre = E2[stok[tid >> 6][tt + 1] * UU + ug * 64 + (tid & 63)];

        // ---- matvec; h(s-1) fragments read ONCE from LDS, SAVED to regs ----
        float acc0[4] = {0.f, 0.f, 0.f, 0.f};
        float acc1[4] = {0.f, 0.f, 0.f, 0.f};
        float hsv0[16], hsv1[16];        // saved h fragments (const-idx after unroll)
        if (s > 0) {
            const float* H0 = hstage[sl][0];
            const float* H1 = hstage[sl][1];
            #pragma unroll
            for (int g = 0; g < 4; ++g) {
                const int as2 = (4 * ks + g) ^ fmv;
                const float4 ha = *(const float4*)(H0 + as2 * 4);
                const float4 hc = *(const float4*)(H1 + as2 * 4);
                const float av[4] = {ha.x, ha.y, ha.z, ha.w};
                const float cv[4] = {hc.x, hc.y, hc.z, hc.w};
                #pragma unroll
                for (int m = 0; m < 4; ++m) {
                    hsv0[g * 4 + m] = av[m];
                    hsv1[g * 4 + m] = cv[m];
                    const float4 wv = whreg[g * 4 + m];
                    acc0[0] = fmaf(av[m], wv.x, acc0[0]);
                    acc0[1] = fmaf(av[m], wv.y, acc0[1]);
                    acc0[2] = fmaf(av[m], wv.z, acc0[2]);
                    acc0[3] = fmaf(av[m], wv.w, acc0[3]);
                    acc1[0] = fmaf(cv[m], wv.x, acc1[0]);
                    acc1[1] = fmaf(cv[m], wv.y, acc1[1]);
                    acc1[2] = fmaf(cv[m], wv.z, acc1[2]);
                    acc1[3] = fmaf(cv[m], wv.w, acc1[3]);
                }
            }
        }
        // deferred xp LDS write (load latency hidden under matvec)
        if (dopre)
            xps[(s + 1) & 1][tid >> 6][tid & 63] = xpre;

        // ---- matvec fold-reduce: 8 vals over 32 ks-lanes in 9 shfls ----
        // (mappings verified R7/R8, absmax 6.1e-5) Result v in EVERY lane:
        // value (b=(ks>>4)&1, c=2*((ks>>3)&1)+((ks>>2)&1)).
        float tba[4];
        #pragma unroll
        for (int c = 0; c < 4; ++c) {
            const float x = (ks & 16) ? acc0[c] : acc1[c];
            const float y = __shfl_xor(x, 16, 64);
            tba[c] = ((ks & 16) ? acc1[c] : acc0[c]) + y;
        }
        float ua, ub;
        {
            const float x0 = (ks & 8) ? tba[0] : tba[2];
            const float x1 = (ks & 8) ? tba[1] : tba[3];
            const float y0 = __shfl_xor(x0, 8, 64);
            const float y1 = __shfl_xor(x1, 8, 64);
            ua = ((ks & 8) ? tba[2] : tba[0]) + y0;
            ub = ((ks & 8) ? tba[3] : tba[1]) + y1;
        }
        float v;
        {
            const float x = (ks & 4) ? ua : ub;
            const float y = __shfl_xor(x, 4, 64);
            v = ((ks & 4) ? ub : ua) + y;
        }
        v += __shfl_xor(v, 1, 64);
        v += __shfl_xor(v, 2, 64);

        // ---- finalize + publish h(s) ASAP: lanes (ks&3)==0 ----
        if ((ks & 3) == 0) {
            const int b = (ks >> 4) & 1;
            const int c = (((ks >> 3) & 1) << 1) | ((ks >> 2) & 1);
            const int u = quad * 4 + c;
            const float h = tanh_fast(v + xps[s & 1][b][u]);
            unsigned long long* dst =
                hpub + ((size_t)(s & 1) * BB + b0 + b) * UU + ug * 64 + u;
            const unsigned long long pk =
                ((unsigned long long)(unsigned int)s << 32) | __float_as_uint(h);
            *(volatile unsigned long long*)dst = pk;   // sc0 local-L2 copy
            __hip_atomic_store(dst, pk, __ATOMIC_RELAXED, __HIP_MEMORY_SCOPE_AGENT);
            hstage[s & 1][b][swz(ug * 16 + quad) * 4 + c] = h;
        }

        // ---- pre-issue poll round 0 for h(s) (next step / epilogue): loads
        //      fly during the logits block below -> RTT hidden ----
        if (w != ug && (tt + 1 < TC || last)) {
            unsigned long long* n0 =
                hpub + ((size_t)(s & 1) * BB + b0) * UU + w * 64 + lane;
            q0 = *(volatile const unsigned long long*)n0;
            q1 = *(volatile const unsigned long long*)(n0 + UU);
            pre = true;
        }

        // ---- logits(s-1) AFTER publish, from SAVED regs (no LDS reads);
        //      hidden in the peers' exchange window (R8-proven overlap) ----
        if (s > 0) {
            float s00 = 0.f, s01 = 0.f, s10 = 0.f, s11 = 0.f;
            #pragma unroll
            for (int g = 0; g < 4; ++g) {
                #pragma unroll
                for (int m = 0; m < 4; ++m) {
                    s00 = fmaf(hsv0[g * 4 + m], wdreg[4 * g + m],      s00);
                    s01 = fmaf(hsv0[g * 4 + m], wdreg[16 + 4 * g + m], s01);
                    s10 = fmaf(hsv1[g * 4 + m], wdreg[4 * g + m],      s10);
                    s11 = fmaf(hsv1[g * 4 + m], wdreg[16 + 4 * g + m], s11);
                }
            }
            // logits fold-reduce: 4 vals over 32 lanes in 6 shfls
            float pa, pb;
            {
                const float x0 = (ks & 16) ? s00 : s10;
                const float x1 = (ks & 16) ? s01 : s11;
                const float y0 = __shfl_xor(x0, 16, 64);
                const float y1 = __shfl_xor(x1, 16, 64);
                pa = ((ks & 16) ? s10 : s00) + y0;
                pb = ((ks & 16) ? s11 : s01) + y1;
            }
            float L;
            {
                const float x = (ks & 8) ? pa : pb;
                const float y = __shfl_xor(x, 8, 64);
                L = ((ks & 8) ? pb : pa) + y;
            }
            L += __shfl_xor(L, 1, 64);
            L += __shfl_xor(L, 2, 64);
            L += __shfl_xor(L, 4, 64);
            if ((ks & 7) == 0) {
                const int b    = (ks >> 4) & 1;
                const int voff = (ks >> 3) & 1;
                out[((size_t)(b0 + b) * TT_ + (s - 1)) * VV + v0 + voff]
                    = L + (voff ? bdv1 : bdv0);
            }
        }
    }

    // ---- last chunk epilogue: logits(1023) needs full h(1023) staged ----
    if (last) {
        const int s  = t0 + TC - 1;          // 1023
        const int sl = s & 1;
        if (w != ug) {   // own slice already in hstage from tt=TC-1 finalize
            unsigned long long* a0 = hpub + ((size_t)sl * BB + b0) * UU + w * 64 + lane;
            unsigned long long* a1 = a0 + UU;
            volatile const unsigned long long* f0 = a0;
            volatile const unsigned long long* f1 = a1;
            const unsigned int want = (unsigned int)s;
            unsigned long long p0 = 0, p1 = 0;
            bool got = false;
            if (pre) {   // round 0 flew under the final logits block
                p0 = q0; p1 = q1;
                got = (__ballot(((unsigned int)(p0 >> 32) == want) &&
                                ((unsigned int)(p1 >> 32) == want))
                       == 0xFFFFFFFFFFFFFFFFull);
            }
            if (!got) {
                for (int it = 0; it < 24; ++it) {
                    p0 = *f0; p1 = *f1;
                    if (__ballot(((unsigned int)(p0 >> 32) == want) &&
                                 ((unsigned int)(p1 >> 32) == want))
                        == 0xFFFFFFFFFFFFFFFFull) { got = true; break; }
                }
            }
            if (!got) {
                while (true) {
                    p0 = __hip_atomic_load(a0, __ATOMIC_RELAXED, __HIP_MEMORY_SCOPE_AGENT);
                    p1 = __hip_atomic_load(a1, __ATOMIC_RELAXED, __HIP_MEMORY_SCOPE_AGENT);
                    if (__ballot(((unsigned int)(p0 >> 32) == want) &&
                                 ((unsigned int)(p1 >> 32) == want))
                        == 0xFFFFFFFFFFFFFFFFull) break;
                    __builtin_amdgcn_s_sleep(1);
                }
            }
            const int aa = w * 16 + (lane >> 2);
            const int fi = swz(aa) * 4 + (lane & 3);
            hstage[sl][0][fi] = __uint_as_float((unsigned int)p0);
            hstage[sl][1][fi] = __uint_as_float((unsigned int)p1);
        }
        __syncthreads();
        {
            const float* H0 = hstage[sl][0];
            const float* H1 = hstage[sl][1];
            float s00 = 0.f, s01 = 0.f, s10 = 0.f, s11 = 0.f;
            #pragma unroll
            for (int g = 0; g < 4; ++g) {
                const int as2 = (4 * ks + g) ^ fmv;
                const float4 ha = *(const float4*)(H0 + as2 * 4);
                const float4 hc = *(const float4*)(H1 + as2 * 4);
                const float av[4] = {ha.x, ha.y, ha.z, ha.w};
                const float cv[4] = {hc.x, hc.y, hc.z, hc.w};
                #pragma unroll
                for (int m = 0; m < 4; ++m) {
                    s00 = fmaf(av[m], wdreg[4 * g + m],      s00);
                    s01 = fmaf(av[m], wdreg[16 + 4 * g + m], s01);
                    s10 = fmaf(cv[m], wdreg[4 * g + m],      s10);
                    s11 = fmaf(cv[m], wdreg[16 + 4 * g + m], s11);
                }
            }
            float pa, pb;
            {
                const float x0 = (ks & 16) ? s00 : s10;
                const float x1 = (ks & 16) ? s01 : s11;
                const float y0 = __shfl_xor(x0, 16, 64);
                const float y1 = __shfl_xor(x1, 16, 64);
                pa = ((ks & 16) ? s10 : s00) + y0;
                pb = ((ks & 16) ? s11 : s01) + y1;
            }
            float L;
            {
                const float x = (ks & 8) ? pa : pb;
                const float y = __shfl_xor(x, 8, 64);
                L = ((ks & 8) ? pb : pa) + y;
            }
            L += __shfl_xor(L, 1, 64);
            L += __shfl_xor(L, 2, 64);
            L += __shfl_xor(L, 4, 64);
            if ((ks & 7) == 0) {
                const int b    = (ks >> 4) & 1;
                const int voff = (ks >> 3) & 1;
                out[((size_t)(b0 + b) * TT_ + s) * VV + v0 + voff]
                    = L + (voff ? bdv1 : bdv0);
            }
        }
    }
}

extern "C" void kernel_launch(void* const* d_in, const int* in_sizes, int n_in,
                              void* d_out, int out_size, void* d_ws, size_t ws_size,
                              hipStream_t stream)
{
    (void)in_sizes; (void)n_in; (void)ws_size; (void)out_size;

    const int*   toks = (const int*)  d_in[0];
    const float* emb  = (const float*)d_in[1];
    const float* Wx   = (const float*)d_in[2];
    const float* Wh   = (const float*)d_in[3];
    const float* bias = (const float*)d_in[4];
    const float* Wd   = (const float*)d_in[5];
    const float* bd   = (const float*)d_in[6];
    float* out = (float*)d_out;

    // ws layout: hpub [2*BB*UU] u64 (512 KB) | E2 [EE*UU] f32 (512 KB)
    unsigned long long* hpub = (unsigned long long*)d_ws;
    float* E2 = (float*)(hpub + 2 * BB * UU);

    // invalidate tags (0xFFFFFFFF matches no step) -> no stale-tag match on first run
    hipMemsetAsync(hpub, 0xFF, (size_t)(2 * BB * UU) * sizeof(unsigned long long), stream);
    e2_kernel<<<EE, UU, 0, stream>>>(emb, Wx, bias, E2);

    for (int c = 0; c < TT_ / TC; ++c) {
        const int t0 = c * TC;
        rnn_chunk_kernel<<<256, 512, 0, stream>>>(
            toks, E2, Wh, Wd, bd, hpub, out, t0, c == (TT_ / TC - 1));
    }
}

// Round 12
// 2296.441 us; speedup vs baseline: 1.4172x; 1.4172x over previous
//
#include <hip/hip_runtime.h>
#include <math.h>

#define BB   64      // batch
#define TT_  1024    // sequence length
#define UU   512     // hidden units
#define VV   256     // vocab (output)
#define EE   256     // embedding dim
#define TC   128     // time chunk (8 dispatches; R11 proved 256 => skew/fallback blowup)

__device__ __forceinline__ float tanh_fast(float x) {
    // tanh(x) = 1 - 2/(e^{2x}+1); abs err ~1e-6 (validated: absmax 6e-5 end-to-end)
    float e = __expf(x + x);
    return 1.f - 2.f * __builtin_amdgcn_rcpf(e + 1.f);
}

// hstage float4-index swizzle (R4/R6-measured: SQ_LDS_BANK_CONFLICT == 0)
__device__ __forceinline__ int swz(int a) {
    return a ^ (((a >> 3) & 7) ^ ((a >> 6) & 1));
}

// ---------------- E2 = emb @ Wx + b : [256, 512] ----------------
__global__ __launch_bounds__(512) void e2_kernel(
    const float* __restrict__ emb, const float* __restrict__ Wx,
    const float* __restrict__ bias, float* __restrict__ E2)
{
    const int v = blockIdx.x;
    const int u = threadIdx.x;
    float acc = bias[u];
    const float* er = emb + v * EE;
    #pragma unroll 8
    for (int e = 0; e < EE; ++e)
        acc = fmaf(er[e], Wx[e * UU + u], acc);
    E2[v * UU + u] = acc;
}

// ---------------- fused recurrence + logits -------------------------------
// 256 blocks (1/CU), 512 thr = 8 waves. bg = bid&31 (2 batches), ug = bid>>5.
// Group-of-8 blocks (same bg, same XCD under round-robin: bids == bg mod 8)
// exchange h via hpub[(slot,b,u)] = (tag<<32|fp32), dual-published (volatile
// sc0 + agent atomic). Poll: bounded sc0 rounds, then agent-scope spin with
// s_sleep (liveness proven; never hangs).
// R11 POST-MORTEM (isolated): TC=256 halved the launch-boundary resyncs ->
// inter-block skew grew past the sc0 window -> agent/HBM fallback + s_sleep
// (FETCH/step +50%, VALUBusy -9pt, per-step +42%). Chunk boundaries are
// load-bearing resync points. REVERTED to TC=128 / no early-poll (= R10, the
// 2271us best). Kept from R11: fused single ballot. New: sc0 window 24->48
// (exits at first success = free on common path; tolerates 2x skew before
// the expensive fallback).
// Schedule per step (R8/R10-proven): poll h(s-1) -> stage -> lgkm-only
// barrier -> matvec (128 FMA, 8 h b128, h saved to regs) -> fold-reduce
// (9 shfl) -> tanh -> PUBLISH -> logits(s-1) from saved regs (64 FMA + 6
// shfl + store, hidden in the exchange window). No atomics, no out memset.
__global__ __launch_bounds__(512)
void rnn_chunk_kernel(
    const int* __restrict__ toks, const float* __restrict__ E2,
    const float* __restrict__ Wh, const float* __restrict__ Wd,
    const float* __restrict__ bd,
    unsigned long long* hpub,     // [2][BB][UU] (tag,val) pairs
    float* out, int t0, int last)
{
    __shared__ __align__(16) float hstage[2][2][UU];   // 8 KB (swizzled)
    __shared__ __align__(16) float xps[2][2][64];      // 1 KB
    __shared__ int stok[2][TC];                        // 1 KB

    const int bid  = blockIdx.x;
    const int bg   = bid & 31;
    const int ug   = bid >> 5;
    const int tid  = threadIdx.x;
    const int w    = tid >> 6;
    const int lane = tid & 63;
    const int b0   = bg * 2;

    // roles: thread (quad, ks) does matvec units [ug*64+quad*4,+4) over
    // k [16ks,+16) AND logits v {ug*32+2quad, +1} over u [16ks,+16)
    const int qsel = lane >> 5;          // 0/1
    const int ks   = lane & 31;          // k/u slice [ks*16, +16)
    const int quad = w * 2 + qsel;       // [0,16)
    const int fmv  = ((ks >> 1) & 7) ^ ((ks >> 4) & 1);   // swz term, a = 4ks+g
    const int v0   = ug * 32 + quad * 2;

    // ---- Wh fragment (RA keeps in scratch -- measured best; vmem pipe
    //      overlaps the DS pipe, which is the real constraint) ----
    float4 whreg[16];                    // whreg[4g+m] = Wh[16ks+4g+m][ug*64+quad*4..+4]
    {
        const float4* Wh4 = (const float4*)Wh;   // [512][128]
        #pragma unroll
        for (int r = 0; r < 16; ++r)
            whreg[r] = Wh4[(ks * 16 + r) * 128 + ug * 16 + quad];
    }
    #pragma unroll
    for (int r = 0; r < 16; ++r) {
        float px = whreg[r].x, py = whreg[r].y, pz = whreg[r].z, pw = whreg[r].w;
        asm volatile("" : "+v"(px), "+v"(py), "+v"(pz), "+v"(pw));
        whreg[r] = make_float4(px, py, pz, pw);
    }

    // ---- Wd column pair -> registers/scratch (32 floats) ----
    float wdreg[32];                     // [j]=Wd[16ks+j][v0], [16+j]=..[v0+1]
    #pragma unroll
    for (int j = 0; j < 16; ++j) {
        const float2 wd2 = *(const float2*)(Wd + (ks * 16 + j) * VV + v0);
        wdreg[j]      = wd2.x;
        wdreg[16 + j] = wd2.y;
    }
    const float bdv0 = bd[v0];
    const float bdv1 = bd[v0 + 1];

    // ---- chunk tokens + xp(t0) staging ----
    if (tid < 256) {
        const int b = tid >> 7, q = tid & 127;
        stok[b][q] = toks[(b0 + b) * TT_ + t0 + q];
    }
    if (tid < 128) {
        const int b = tid >> 6, u = tid & 63;
        xps[0][b][u] = E2[toks[(b0 + b) * TT_ + t0] * UU + ug * 64 + u];
    }
    __syncthreads();

    for (int tt = 0; tt < TC; ++tt) {
        const int s  = t0 + tt;
        const int sl = (s - 1) & 1;

        // ---- poll h(s-1) (skip own slice except at chunk start) ----
        if (s > 0 && (w != ug || tt == 0)) {
            unsigned long long* a0 = hpub + ((size_t)sl * BB + b0) * UU + w * 64 + lane;
            unsigned long long* a1 = a0 + UU;
            volatile const unsigned long long* f0 = a0;
            volatile const unsigned long long* f1 = a1;
            const unsigned int want = (unsigned int)(s - 1);
            unsigned long long p0 = 0, p1 = 0;
            bool got = false;
            for (int it = 0; it < 48; ++it) {     // sc0 fast rounds (local-XCD L2);
                p0 = *f0; p1 = *f1;               // 48 tolerates 2x skew vs 24
                if (__ballot(((unsigned int)(p0 >> 32) == want) &&
                             ((unsigned int)(p1 >> 32) == want))
                    == 0xFFFFFFFFFFFFFFFFull) { got = true; break; }
            }
            if (!got) {                           // proven agent-scope fallback
                while (true) {
                    p0 = __hip_atomic_load(a0, __ATOMIC_RELAXED, __HIP_MEMORY_SCOPE_AGENT);
                    p1 = __hip_atomic_load(a1, __ATOMIC_RELAXED, __HIP_MEMORY_SCOPE_AGENT);
                    if (__ballot(((unsigned int)(p0 >> 32) == want) &&
                                 ((unsigned int)(p1 >> 32) == want))
                        == 0xFFFFFFFFFFFFFFFFull) break;
                    __builtin_amdgcn_s_sleep(1);
                }
            }
            // stage swizzled: u = w*64+lane -> float4 a = w*16+(lane>>2), elem lane&3
            const int aa = w * 16 + (lane >> 2);
            const int fi = swz(aa) * 4 + (lane & 3);
            hstage[sl][0][fi] = __uint_as_float((unsigned int)p0);
            hstage[sl][1][fi] = __uint_as_float((unsigned int)p1);
        }
        // RAW barrier: order LDS (lgkmcnt) but let publish/out stores and
        // prefetch loads stay in flight (no vmcnt(0) drain).
        asm volatile("s_waitcnt lgkmcnt(0)" ::: "memory");
        __builtin_amdgcn_s_barrier();

        // ---- xp prefetch for s+1: issue load now, LDS-write after matvec ----
        float xpre = 0.f;
        const bool dopre = (tid < 128) && (tt + 1 < TC);
        if (dopre)
            xpre = E2[stok[tid >> 6][tt + 1] * UU + ug * 64 + (tid & 63)];

        // ---- matvec; h(s-1) fragments read ONCE from LDS, SAVED to regs ----
        float acc0[4] = {0.f, 0.f, 0.f, 0.f};
        float acc1[4] = {0.f, 0.f, 0.f, 0.f};
        float hsv0[16], hsv1[16];        // saved h fragments (const-idx after unroll)
        if (s > 0) {
            const float* H0 = hstage[sl][0];
            const float* H1 = hstage[sl][1];
            #pragma unroll
            for (int g = 0; g < 4; ++g) {
                const int as2 = (4 * ks + g) ^ fmv;
                const float4 ha = *(const float4*)(H0 + as2 * 4);
                const float4 hc = *(const float4*)(H1 + as2 * 4);
                const float av[4] = {ha.x, ha.y, ha.z, ha.w};
                const float cv[4] = {hc.x, hc.y, hc.z, hc.w};
                #pragma unroll
                for (int m = 0; m < 4; ++m) {
                    hsv0[g * 4 + m] = av[m];
                    hsv1[g * 4 + m] = cv[m];
                    const float4 wv = whreg[g * 4 + m];
                    acc0[0] = fmaf(av[m], wv.x, acc0[0]);
                    acc0[1] = fmaf(av[m], wv.y, acc0[1]);
                    acc0[2] = fmaf(av[m], wv.z, acc0[2]);
                    acc0[3] = fmaf(av[m], wv.w, acc0[3]);
                    acc1[0] = fmaf(cv[m], wv.x, acc1[0]);
                    acc1[1] = fmaf(cv[m], wv.y, acc1[1]);
                    acc1[2] = fmaf(cv[m], wv.z, acc1[2]);
                    acc1[3] = fmaf(cv[m], wv.w, acc1[3]);
                }
            }
        }
        // deferred xp LDS write (load latency hidden under matvec)
        if (dopre)
            xps[(s + 1) & 1][tid >> 6][tid & 63] = xpre;

        // ---- matvec fold-reduce: 8 vals over 32 ks-lanes in 9 shfls ----
        // (mappings verified R7/R8, absmax 6.1e-5) Result v in EVERY lane:
        // value (b=(ks>>4)&1, c=2*((ks>>3)&1)+((ks>>2)&1)).
        float tba[4];
        #pragma unroll
        for (int c = 0; c < 4; ++c) {
            const float x = (ks & 16) ? acc0[c] : acc1[c];
            const float y = __shfl_xor(x, 16, 64);
            tba[c] = ((ks & 16) ? acc1[c] : acc0[c]) + y;
        }
        float ua, ub;
        {
            const float x0 = (ks & 8) ? tba[0] : tba[2];
            const float x1 = (ks & 8) ? tba[1] : tba[3];
            const float y0 = __shfl_xor(x0, 8, 64);
            const float y1 = __shfl_xor(x1, 8, 64);
            ua = ((ks & 8) ? tba[2] : tba[0]) + y0;
            ub = ((ks & 8) ? tba[3] : tba[1]) + y1;
        }
        float v;
        {
            const float x = (ks & 4) ? ua : ub;
            const float y = __shfl_xor(x, 4, 64);
            v = ((ks & 4) ? ub : ua) + y;
        }
        v += __shfl_xor(v, 1, 64);
        v += __shfl_xor(v, 2, 64);

        // ---- finalize + publish h(s) ASAP: lanes (ks&3)==0 ----
        if ((ks & 3) == 0) {
            const int b = (ks >> 4) & 1;
            const int c = (((ks >> 3) & 1) << 1) | ((ks >> 2) & 1);
            const int u = quad * 4 + c;
            const float h = tanh_fast(v + xps[s & 1][b][u]);
            unsigned long long* dst =
                hpub + ((size_t)(s & 1) * BB + b0 + b) * UU + ug * 64 + u;
            const unsigned long long pk =
                ((unsigned long long)(unsigned int)s << 32) | __float_as_uint(h);
            *(volatile unsigned long long*)dst = pk;   // sc0 local-L2 copy
            __hip_atomic_store(dst, pk, __ATOMIC_RELAXED, __HIP_MEMORY_SCOPE_AGENT);
            hstage[s & 1][b][swz(ug * 16 + quad) * 4 + c] = h;
        }

        // ---- logits(s-1) AFTER publish, from SAVED regs (no LDS reads);
        //      hidden in the peers' exchange window (R8-proven overlap) ----
        if (s > 0) {
            float s00 = 0.f, s01 = 0.f, s10 = 0.f, s11 = 0.f;
            #pragma unroll
            for (int g = 0; g < 4; ++g) {
                #pragma unroll
                for (int m = 0; m < 4; ++m) {
                    s00 = fmaf(hsv0[g * 4 + m], wdreg[4 * g + m],      s00);
                    s01 = fmaf(hsv0[g * 4 + m], wdreg[16 + 4 * g + m], s01);
                    s10 = fmaf(hsv1[g * 4 + m], wdreg[4 * g + m],      s10);
                    s11 = fmaf(hsv1[g * 4 + m], wdreg[16 + 4 * g + m], s11);
                }
            }
            // logits fold-reduce: 4 vals over 32 lanes in 6 shfls
            float pa, pb;
            {
                const float x0 = (ks & 16) ? s00 : s10;
                const float x1 = (ks & 16) ? s01 : s11;
                const float y0 = __shfl_xor(x0, 16, 64);
                const float y1 = __shfl_xor(x1, 16, 64);
                pa = ((ks & 16) ? s10 : s00) + y0;
                pb = ((ks & 16) ? s11 : s01) + y1;
            }
            float L;
            {
                const float x = (ks & 8) ? pa : pb;
                const float y = __shfl_xor(x, 8, 64);
                L = ((ks & 8) ? pb : pa) + y;
            }
            L += __shfl_xor(L, 1, 64);
            L += __shfl_xor(L, 2, 64);
            L += __shfl_xor(L, 4, 64);
            if ((ks & 7) == 0) {
                const int b    = (ks >> 4) & 1;
                const int voff = (ks >> 3) & 1;
                out[((size_t)(b0 + b) * TT_ + (s - 1)) * VV + v0 + voff]
                    = L + (voff ? bdv1 : bdv0);
            }
        }
    }

    // ---- last chunk epilogue: logits(1023) needs full h(1023) staged ----
    if (last) {
        const int s  = t0 + TC - 1;          // 1023
        const int sl = s & 1;
        if (w != ug) {   // own slice already in hstage from tt=TC-1 finalize
            unsigned long long* a0 = hpub + ((size_t)sl * BB + b0) * UU + w * 64 + lane;
            unsigned long long* a1 = a0 + UU;
            volatile const unsigned long long* f0 = a0;
            volatile const unsigned long long* f1 = a1;
            const unsigned int want = (unsigned int)s;
            unsigned long long p0 = 0, p1 = 0;
            bool got = false;
            for (int it = 0; it < 48; ++it) {
                p0 = *f0; p1 = *f1;
                if (__ballot(((unsigned int)(p0 >> 32) == want) &&
                             ((unsigned int)(p1 >> 32) == want))
                    == 0xFFFFFFFFFFFFFFFFull) { got = true; break; }
            }
            if (!got) {
                while (true) {
                    p0 = __hip_atomic_load(a0, __ATOMIC_RELAXED, __HIP_MEMORY_SCOPE_AGENT);
                    p1 = __hip_atomic_load(a1, __ATOMIC_RELAXED, __HIP_MEMORY_SCOPE_AGENT);
                    if (__ballot(((unsigned int)(p0 >> 32) == want) &&
                                 ((unsigned int)(p1 >> 32) == want))
                        == 0xFFFFFFFFFFFFFFFFull) break;
                    __builtin_amdgcn_s_sleep(1);
                }
            }
            const int aa = w * 16 + (lane >> 2);
            const int fi = swz(aa) * 4 + (lane & 3);
            hstage[sl][0][fi] = __uint_as_float((unsigned int)p0);
            hstage[sl][1][fi] = __uint_as_float((unsigned int)p1);
        }
        __syncthreads();
        {
            const float* H0 = hstage[sl][0];
            const float* H1 = hstage[sl][1];
            float s00 = 0.f, s01 = 0.f, s10 = 0.f, s11 = 0.f;
            #pragma unroll
            for (int g = 0; g < 4; ++g) {
                const int as2 = (4 * ks + g) ^ fmv;
                const float4 ha = *(const float4*)(H0 + as2 * 4);
                const float4 hc = *(const float4*)(H1 + as2 * 4);
                const float av[4] = {ha.x, ha.y, ha.z, ha.w};
                const float cv[4] = {hc.x, hc.y, hc.z, hc.w};
                #pragma unroll
                for (int m = 0; m < 4; ++m) {
                    s00 = fmaf(av[m], wdreg[4 * g + m],      s00);
                    s01 = fmaf(av[m], wdreg[16 + 4 * g + m], s01);
                    s10 = fmaf(cv[m], wdreg[4 * g + m],      s10);
                    s11 = fmaf(cv[m], wdreg[16 + 4 * g + m], s11);
                }
            }
            float pa, pb;
            {
                const float x0 = (ks & 16) ? s00 : s10;
                const float x1 = (ks & 16) ? s01 : s11;
                const float y0 = __shfl_xor(x0, 16, 64);
                const float y1 = __shfl_xor(x1, 16, 64);
                pa = ((ks & 16) ? s10 : s00) + y0;
                pb = ((ks & 16) ? s11 : s01) + y1;
            }
            float L;
            {
                const float x = (ks & 8) ? pa : pb;
                const float y = __shfl_xor(x, 8, 64);
                L = ((ks & 8) ? pb : pa) + y;
            }
            L += __shfl_xor(L, 1, 64);
            L += __shfl_xor(L, 2, 64);
            L += __shfl_xor(L, 4, 64);
            if ((ks & 7) == 0) {
                const int b    = (ks >> 4) & 1;
                const int voff = (ks >> 3) & 1;
                out[((size_t)(b0 + b) * TT_ + s) * VV + v0 + voff]
                    = L + (voff ? bdv1 : bdv0);
            }
        }
    }
}

extern "C" void kernel_launch(void* const* d_in, const int* in_sizes, int n_in,
                              void* d_out, int out_size, void* d_ws, size_t ws_size,
                              hipStream_t stream)
{
    (void)in_sizes; (void)n_in; (void)ws_size; (void)out_size;

    const int*   toks = (const int*)  d_in[0];
    const float* emb  = (const float*)d_in[1];
    const float* Wx   = (const float*)d_in[2];
    const float* Wh   = (const float*)d_in[3];
    const float* bias = (const float*)d_in[4];
    const float* Wd   = (const float*)d_in[5];
    const float* bd   = (const float*)d_in[6];
    float* out = (float*)d_out;

    // ws layout: hpub [2*BB*UU] u64 (512 KB) | E2 [EE*UU] f32 (512 KB)
    unsigned long long* hpub = (unsigned long long*)d_ws;
    float* E2 = (float*)(hpub + 2 * BB * UU);

    // invalidate tags (0xFFFFFFFF matches no step) -> no stale-tag match on first run
    hipMemsetAsync(hpub, 0xFF, (size_t)(2 * BB * UU) * sizeof(unsigned long long), stream);
    e2_kernel<<<EE, UU, 0, stream>>>(emb, Wx, bias, E2);

    for (int c = 0; c < TT_ / TC; ++c) {
        const int t0 = c * TC;
        rnn_chunk_kernel<<<256, 512, 0, stream>>>(
            toks, E2, Wh, Wd, bd, hpub, out, t0, c == (TT_ / TC - 1));
    }
}